// Round 6
// baseline (818.105 us; speedup 1.0000x reference)
//
#include <hip/hip_runtime.h>
#include <hip/hip_bf16.h>

// Problem constants (fixed by reference)
#define D_MODEL 256
#define NHEAD   8
#define NLEV    4
#define NPTS    4
#define HDIM    32
#define DFFN    512
#define NBATCH  8
#define LQ      1000
#define LIN     21760            // 128*128 + 64*64 + 32*32 + 16*16
#define M_VAL   (NBATCH * LIN)   // 174080
#define M_Q     (NBATCH * LQ)    // 8000
#define NPANEL  (M_VAL / 128)    // 1360

typedef __attribute__((ext_vector_type(8))) short short8;
typedef __attribute__((ext_vector_type(4))) short short4v;
typedef __attribute__((ext_vector_type(4))) float f32x4;

struct alignas(8) bf16x4 { __hip_bfloat16 a, b, c, d; };

__device__ __forceinline__ short f2bf(float f) {
    __hip_bfloat16 h = __float2bfloat16(f);
    return *reinterpret_cast<short*>(&h);
}
__device__ __forceinline__ float bf2f(short s) {
    return __uint_as_float(((unsigned)(unsigned short)s) << 16);
}

// ---------------------------------------------------------------------------
// Weight prep: transpose f32 [K][N] -> bf16 [N][K] for MFMA B-operand.
// ---------------------------------------------------------------------------
__global__ __launch_bounds__(256)
void transpose_weights_kernel(const float* __restrict__ Wv, const float* __restrict__ Wo,
                              const float* __restrict__ W1, const float* __restrict__ W2,
                              short* __restrict__ Wv_t, short* __restrict__ Wo_t,
                              short* __restrict__ W1_t, short* __restrict__ W2_t)
{
    const int b = blockIdx.x;
    const float* src; short* dst; int K, N, tb;
    if (b < 64)       { src = Wv; dst = Wv_t; K = 256; N = 256; tb = b; }
    else if (b < 128) { src = Wo; dst = Wo_t; K = 256; N = 256; tb = b - 64; }
    else if (b < 256) { src = W1; dst = W1_t; K = 256; N = 512; tb = b - 128; }
    else              { src = W2; dst = W2_t; K = 512; N = 256; tb = b - 256; }
    const int ntn = N >> 5;
    const int kt = tb / ntn, nt = tb % ntn;
    __shared__ float t[32][33];
    const int x = threadIdx.x & 31, y = threadIdx.x >> 5;
    #pragma unroll
    for (int j = 0; j < 4; ++j)
        t[y + 8*j][x] = src[(kt*32 + y + 8*j) * N + nt*32 + x];
    __syncthreads();
    #pragma unroll
    for (int j = 0; j < 4; ++j)
        dst[(nt*32 + y + 8*j) * K + kt*32 + x] = f2bf(t[x][y + 8*j]);
}

// ---------------------------------------------------------------------------
// B-stationary value GEMM: value = src @ W_value + b_value (masked), bf16
// head-plane output. Whole B (256x256 bf16 = 128KB) lives in LDS for the
// block's lifetime; loaded ONCE with chunk-XOR-swizzled SOURCE address so
// ds_read_b128 frag reads are bank-spread. A is streamed global->reg
// (f32 -> bf16 cvt in-reg). ZERO barriers in the steady state.
// 512 threads = 8 waves; wave w owns rows w*16..w*16+15 of each 128-row
// panel; 2 panels per block (grid 680 = NPANEL/2 exactly).
// LDS chunk swizzle: LDS[n][kp] = B[n][kp ^ ((n&7)<<3)]  (8-elem chunks).
// NOTE: 128KB dynamic LDS requires hipFuncSetAttribute (done in launch).
// VGPR budget: A[16] f4 (64) + acc[16] f32x4 (64) + misc ~ 170 < 256 cap.
// ---------------------------------------------------------------------------
__global__ __launch_bounds__(512, 2)
void value_gemm_kernel(const float* __restrict__ src, const short* __restrict__ Bt,
                       const float* __restrict__ bias, const unsigned char* __restrict__ mask,
                       __hip_bfloat16* __restrict__ value)
{
    extern __shared__ short Bs[];   // 256*256 bf16 = 128KB (dynamic)
    const int tid  = threadIdx.x;
    const int lane = tid & 63, wid = tid >> 6;
    const int l15 = lane & 15, l4 = lane >> 4;

    // ---- load B once (swizzled source) ----
    #pragma unroll
    for (int i = 0; i < 16; ++i) {
        const int e  = i * 4096 + tid * 8;     // linear LDS elem
        const int n  = e >> 8, kp = e & 255;
        const int k  = kp ^ ((n & 7) << 3);
        *reinterpret_cast<short8*>(&Bs[e]) =
            *reinterpret_cast<const short8*>(&Bt[n * 256 + k]);
    }
    // per-lane bias for its 16 columns (loop-invariant)
    float biasv[16];
    #pragma unroll
    for (int n4 = 0; n4 < 16; ++n4) biasv[n4] = bias[n4 * 16 + l15];
    __syncthreads();

    const int p0   = blockIdx.x * 2;
    const int rowA = wid * 16 + l15;           // A-row within panel (frag row)
    const int kb0  = l4 * 8;                   // lane's k-base within 32-chunk

    float4 A[16];
    f32x4 acc[16];

    #pragma unroll 1
    for (int pan = 0; pan < 2; ++pan) {
        const int p = p0 + pan;
        const float* ap = src + ((long)(p * 128) + rowA) * 256 + kb0;

        #pragma unroll
        for (int kk = 0; kk < 8; ++kk) {
            A[2*kk]   = *reinterpret_cast<const float4*>(ap + kk * 32);
            A[2*kk+1] = *reinterpret_cast<const float4*>(ap + kk * 32 + 4);
        }
        #pragma unroll
        for (int n4 = 0; n4 < 16; ++n4) acc[n4] = (f32x4){0.f, 0.f, 0.f, 0.f};

        #pragma unroll
        for (int kk = 0; kk < 8; ++kk) {
            const float4 lo = A[2*kk], hi = A[2*kk+1];
            short8 af;
            af[0] = f2bf(lo.x); af[1] = f2bf(lo.y); af[2] = f2bf(lo.z); af[3] = f2bf(lo.w);
            af[4] = f2bf(hi.x); af[5] = f2bf(hi.y); af[6] = f2bf(hi.z); af[7] = f2bf(hi.w);
            const int kb = kk * 32 + kb0;
            #pragma unroll
            for (int n4 = 0; n4 < 16; ++n4) {
                const int nr = n4 * 16 + l15;
                const short8 bf = *reinterpret_cast<const short8*>(
                    &Bs[nr * 256 + (kb ^ ((nr & 7) << 3))]);
                acc[n4] = __builtin_amdgcn_mfma_f32_16x16x32_bf16(af, bf, acc[n4], 0, 0, 0);
            }
        }

        // epilogue: bias, mask, head-plane bf16 store
        const int rbase = p * 128 + wid * 16 + l4 * 4;
        bool mk[4];
        #pragma unroll
        for (int r = 0; r < 4; ++r) mk[r] = mask[rbase + r] != 0;
        #pragma unroll
        for (int n4 = 0; n4 < 16; ++n4) {
            const int col = n4 * 16 + l15;
            __hip_bfloat16* vp = value + (size_t)(col >> 5) * ((size_t)M_VAL * HDIM) + (col & 31);
            #pragma unroll
            for (int r = 0; r < 4; ++r) {
                float v = acc[n4][r] + biasv[n4];
                if (mk[r]) v = 0.f;
                vp[(size_t)(rbase + r) * HDIM] = __float2bfloat16(v);
            }
        }
    }
}

// ---------------------------------------------------------------------------
// bf16 MFMA GEMM (FFN1): C = A @ Bt^T + bias, ReLU, bf16 out.
// BM=64 BN=128 BK=64, 256 threads, 4 waves (2x2). Lane-dense staging.
// ---------------------------------------------------------------------------
#define BM 64
#define BN 128
#define BK 64

__global__ __launch_bounds__(256)
void ffn1_gemm_kernel(const float* __restrict__ Ain, const short* __restrict__ Bt,
                      const float* __restrict__ bias, __hip_bfloat16* __restrict__ Cb,
                      int M, int N, int K)
{
    __shared__ short As[BM * BK];
    __shared__ short Bs[BN * BK];
    const int tid  = threadIdx.x;
    const int lane = tid & 63, wid = tid >> 6;
    const int wr = wid >> 1, wc = wid & 1;
    const long bm = (long)blockIdx.y * BM;
    const int  bn = blockIdx.x * BN;

    f32x4 acc[2][4];
    #pragma unroll
    for (int m = 0; m < 2; ++m)
        #pragma unroll
        for (int n = 0; n < 4; ++n)
            acc[m][n] = (f32x4){0.f, 0.f, 0.f, 0.f};

    const int arf = tid >> 4;          // f32 A row base, +16/instr
    const int akf = (tid & 15) * 4;
    const int arh = tid >> 3;          // B row base, +32/instr
    const int akh = (tid & 7) * 8;

    float4 a_f[4];
    short8 b_r[4];

    auto load_tile = [&](int k0) {
        const float* Ap = Ain + (long)(k0 + akf);
        #pragma unroll
        for (int i = 0; i < 4; ++i)
            a_f[i] = *reinterpret_cast<const float4*>(Ap + (bm + arf + 16*i) * (long)K);
        const short* Bp = Bt + (long)(k0 + akh);
        #pragma unroll
        for (int i = 0; i < 4; ++i)
            b_r[i] = *reinterpret_cast<const short8*>(Bp + (bn + arh + 32*i) * (long)K);
    };
    auto store_tile = [&]() {
        #pragma unroll
        for (int i = 0; i < 4; ++i) {
            const int r = arf + 16*i;
            short4v s;
            s[0] = f2bf(a_f[i].x); s[1] = f2bf(a_f[i].y);
            s[2] = f2bf(a_f[i].z); s[3] = f2bf(a_f[i].w);
            *reinterpret_cast<short4v*>(&As[r * BK + (akf ^ ((r & 7) << 3))]) = s;
        }
        #pragma unroll
        for (int i = 0; i < 4; ++i) {
            const int r = arh + 32*i;
            *reinterpret_cast<short8*>(&Bs[r * BK + (akh ^ ((r & 7) << 3))]) = b_r[i];
        }
    };

    load_tile(0);
    const int nsteps = K / BK;
    for (int s = 0; s < nsteps; ++s) {
        store_tile();
        __syncthreads();
        if (s + 1 < nsteps) load_tile((s + 1) * BK);
        #pragma unroll
        for (int kk = 0; kk < 2; ++kk) {
            const int kb = kk * 32 + (lane >> 4) * 8;
            short8 af[2], bfr[4];
            #pragma unroll
            for (int m = 0; m < 2; ++m) {
                const int row = wr * 32 + m * 16 + (lane & 15);
                af[m] = *reinterpret_cast<const short8*>(&As[row * BK + (kb ^ ((row & 7) << 3))]);
            }
            #pragma unroll
            for (int n = 0; n < 4; ++n) {
                const int row = wc * 64 + n * 16 + (lane & 15);
                bfr[n] = *reinterpret_cast<const short8*>(&Bs[row * BK + (kb ^ ((row & 7) << 3))]);
            }
            #pragma unroll
            for (int m = 0; m < 2; ++m)
                #pragma unroll
                for (int n = 0; n < 4; ++n)
                    acc[m][n] = __builtin_amdgcn_mfma_f32_16x16x32_bf16(af[m], bfr[n], acc[m][n], 0, 0, 0);
        }
        __syncthreads();
    }

    #pragma unroll
    for (int m = 0; m < 2; ++m) {
        #pragma unroll
        for (int n = 0; n < 4; ++n) {
            const int col = bn + wc * 64 + n * 16 + (lane & 15);
            const float bc = bias[col];
            #pragma unroll
            for (int r = 0; r < 4; ++r) {
                const long row = bm + wr * 32 + m * 16 + (lane >> 4) * 4 + r;
                float v = fmaxf(acc[m][n][r] + bc, 0.f);
                Cb[row * (long)N + col] = __float2bfloat16(v);
            }
        }
    }
}

// ---------------------------------------------------------------------------
// Fused GEMM + bias + residual + LayerNorm. N = 256 (full row per block).
// A bf16 [M][K], Bt bf16 [256][K]. BM=64, 256 threads = 4 waves (1x4),
// wave wc owns cols wc*64..+63 of all 64 rows. Cross-wave LN via LDS.
// ---------------------------------------------------------------------------
template<int KDIM>
__global__ __launch_bounds__(256)
void gemm_ln_kernel(const __hip_bfloat16* __restrict__ Abf, const short* __restrict__ Bt,
                    const float* __restrict__ bias, const float* __restrict__ residual,
                    const float* __restrict__ g, const float* __restrict__ be,
                    float* __restrict__ out)
{
    __shared__ short As[64 * BK];
    __shared__ short Bs[256 * BK];
    __shared__ float red[64][4][2];
    __shared__ float mrs[64][2];

    const int tid  = threadIdx.x;
    const int lane = tid & 63, wc = tid >> 6;
    const int l15 = lane & 15, l4 = lane >> 4;
    const long bm = (long)blockIdx.x * 64;

    f32x4 acc[4][4];
    #pragma unroll
    for (int m = 0; m < 4; ++m)
        #pragma unroll
        for (int n = 0; n < 4; ++n)
            acc[m][n] = (f32x4){0.f, 0.f, 0.f, 0.f};

    const int arh = tid >> 3;          // +32 per instr
    const int akh = (tid & 7) * 8;
    const short* Ain = reinterpret_cast<const short*>(Abf);

    short8 a_r[2], b_r[8];
    auto load_tile = [&](int k0) {
        const short* Ap = Ain + (long)(k0 + akh);
        #pragma unroll
        for (int i = 0; i < 2; ++i)
            a_r[i] = *reinterpret_cast<const short8*>(Ap + (bm + arh + 32*i) * (long)KDIM);
        const short* Bp = Bt + (long)(k0 + akh);
        #pragma unroll
        for (int i = 0; i < 8; ++i)
            b_r[i] = *reinterpret_cast<const short8*>(Bp + (arh + 32*i) * (long)KDIM);
    };
    auto store_tile = [&]() {
        #pragma unroll
        for (int i = 0; i < 2; ++i) {
            const int r = arh + 32*i;
            *reinterpret_cast<short8*>(&As[r * BK + (akh ^ ((r & 7) << 3))]) = a_r[i];
        }
        #pragma unroll
        for (int i = 0; i < 8; ++i) {
            const int r = arh + 32*i;
            *reinterpret_cast<short8*>(&Bs[r * BK + (akh ^ ((r & 7) << 3))]) = b_r[i];
        }
    };

    load_tile(0);
    #pragma unroll
    for (int s = 0; s < KDIM / BK; ++s) {
        store_tile();
        __syncthreads();
        if (s + 1 < KDIM / BK) load_tile((s + 1) * BK);
        #pragma unroll
        for (int kk = 0; kk < 2; ++kk) {
            const int kb = kk * 32 + l4 * 8;
            short8 af[4], bfr[4];
            #pragma unroll
            for (int m = 0; m < 4; ++m) {
                const int row = m * 16 + l15;
                af[m] = *reinterpret_cast<const short8*>(&As[row * BK + (kb ^ ((row & 7) << 3))]);
            }
            #pragma unroll
            for (int n = 0; n < 4; ++n) {
                const int row = wc * 64 + n * 16 + l15;
                bfr[n] = *reinterpret_cast<const short8*>(&Bs[row * BK + (kb ^ ((row & 7) << 3))]);
            }
            #pragma unroll
            for (int m = 0; m < 4; ++m)
                #pragma unroll
                for (int n = 0; n < 4; ++n)
                    acc[m][n] = __builtin_amdgcn_mfma_f32_16x16x32_bf16(af[m], bfr[n], acc[m][n], 0, 0, 0);
        }
        __syncthreads();
    }

    // ---- epilogue: bias + residual, cross-wave LN, normalize, store ----
    float gv[4], bev[4], bi[4];
    #pragma unroll
    for (int n = 0; n < 4; ++n) {
        const int c = wc * 64 + n * 16 + l15;
        gv[n] = g[c]; bev[n] = be[c]; bi[n] = bias[c];
    }
    #pragma unroll
    for (int m = 0; m < 4; ++m) {
        #pragma unroll
        for (int r = 0; r < 4; ++r) {
            const int lrow = m * 16 + l4 * 4 + r;
            const long grow = bm + lrow;
            float s = 0.f, q = 0.f;
            #pragma unroll
            for (int n = 0; n < 4; ++n) {
                const int c = wc * 64 + n * 16 + l15;
                float v = acc[m][n][r] + bi[n] + residual[grow * 256 + c];
                acc[m][n][r] = v;
                s += v; q += v * v;
            }
            #pragma unroll
            for (int msk = 1; msk < 16; msk <<= 1) {
                s += __shfl_xor(s, msk, 64);
                q += __shfl_xor(q, msk, 64);
            }
            if (l15 == 0) { red[lrow][wc][0] = s; red[lrow][wc][1] = q; }
        }
    }
    __syncthreads();
    if (tid < 64) {
        float S = 0.f, Q = 0.f;
        #pragma unroll
        for (int w = 0; w < 4; ++w) { S += red[tid][w][0]; Q += red[tid][w][1]; }
        const float mean = S * (1.f / 256.f);
        const float var  = Q * (1.f / 256.f) - mean * mean;
        mrs[tid][0] = mean;
        mrs[tid][1] = rsqrtf(var + 1e-5f);
    }
    __syncthreads();
    #pragma unroll
    for (int m = 0; m < 4; ++m) {
        #pragma unroll
        for (int r = 0; r < 4; ++r) {
            const int lrow = m * 16 + l4 * 4 + r;
            const long grow = bm + lrow;
            const float mean = mrs[lrow][0], rs = mrs[lrow][1];
            #pragma unroll
            for (int n = 0; n < 4; ++n) {
                const int c = wc * 64 + n * 16 + l15;
                out[grow * 256 + c] = (acc[m][n][r] - mean) * rs * gv[n] + bev[n];
            }
        }
    }
}

// ---------------------------------------------------------------------------
// Fused off+attn projection, f32 SIMT (precision-sensitive), 2-phase prefetch.
// ---------------------------------------------------------------------------
__global__ __launch_bounds__(256)
void proj_gemm_kernel(const float* __restrict__ A, const float* __restrict__ A2,
                      const float* __restrict__ Wo, const float* __restrict__ bo,
                      const float* __restrict__ Wa, const float* __restrict__ ba,
                      float* __restrict__ Co, float* __restrict__ Ca)
{
    __shared__ float As[16][68];
    __shared__ float Bs[16][64];
    const int tid = threadIdx.x;
    const long bm = (long)blockIdx.y * 64;
    const int  bn = blockIdx.x * 64;
    const float* B; const float* bias; float* C; int Nc, cb;
    if (bn < 256) { B = Wo; bias = bo; C = Co; Nc = 256; cb = bn; }
    else          { B = Wa; bias = ba; C = Ca; Nc = 128; cb = bn - 256; }

    const int tx = tid & 15, ty = tid >> 4;
    const int ar = tid >> 2, ac = (tid & 3) * 4;
    float acc[4][4] = {};
    const float* Aptr = A  + (bm + ar) * 256L + ac;
    const float* A2p  = A2 + (bm + ar) * 256L + ac;
    const float* Bptr = B + (long)ty * Nc + cb + tx * 4;

    float4 av, a2, bv;
    auto load = [&](int k0) {
        av = *reinterpret_cast<const float4*>(Aptr + k0);
        a2 = *reinterpret_cast<const float4*>(A2p + k0);
        bv = *reinterpret_cast<const float4*>(Bptr + (long)k0 * Nc);
    };
    load(0);
    for (int k0 = 0; k0 < 256; k0 += 16) {
        As[ac + 0][ar] = av.x + a2.x;
        As[ac + 1][ar] = av.y + a2.y;
        As[ac + 2][ar] = av.z + a2.z;
        As[ac + 3][ar] = av.w + a2.w;
        *reinterpret_cast<float4*>(&Bs[ty][tx * 4]) = bv;
        __syncthreads();
        if (k0 + 16 < 256) load(k0 + 16);
        #pragma unroll
        for (int kk = 0; kk < 16; ++kk) {
            float4 a4 = *reinterpret_cast<const float4*>(&As[kk][ty * 4]);
            float4 b4 = *reinterpret_cast<const float4*>(&Bs[kk][tx * 4]);
            float a[4] = {a4.x, a4.y, a4.z, a4.w};
            float b[4] = {b4.x, b4.y, b4.z, b4.w};
            #pragma unroll
            for (int i = 0; i < 4; ++i)
                #pragma unroll
                for (int j = 0; j < 4; ++j)
                    acc[i][j] = fmaf(a[i], b[j], acc[i][j]);
        }
        __syncthreads();
    }
    const float4 bias4 = *reinterpret_cast<const float4*>(bias + cb + tx * 4);
    #pragma unroll
    for (int i = 0; i < 4; ++i) {
        const long row = bm + ty * 4 + i;
        *reinterpret_cast<float4*>(C + row * Nc + cb + tx * 4) = make_float4(
            acc[i][0] + bias4.x, acc[i][1] + bias4.y,
            acc[i][2] + bias4.z, acc[i][3] + bias4.w);
    }
}

// ---------------------------------------------------------------------------
// Fused softmax + multi-scale deformable sampling (v3, unchanged).
// ---------------------------------------------------------------------------
__global__ __launch_bounds__(128)
void msdeform_sample_kernel(const float* __restrict__ off,
                            const float* __restrict__ logits,
                            const float* __restrict__ ref_pts,
                            const __hip_bfloat16* __restrict__ value,
                            __hip_bfloat16* __restrict__ samp)
{
    const int qi = blockIdx.x;
    const int n  = qi / LQ;
    const int t  = threadIdx.x;

    __shared__ int   s_base[128];
    __shared__ float s_wx[128][2];
    __shared__ float s_wy[128][2];

    {   // phase 1
        const int h = t >> 4, lp = t & 15, l = lp >> 2;
        const float lg = logits[qi * 128 + t];
        float mx = lg;
        #pragma unroll
        for (int m = 1; m < 16; m <<= 1) mx = fmaxf(mx, __shfl_xor(mx, m, 64));
        const float e = __expf(lg - mx);
        float ssum = e;
        #pragma unroll
        for (int m = 1; m < 16; m <<= 1) ssum += __shfl_xor(ssum, m, 64);
        const float w = e / ssum;

        const int Wl = 128 >> l;
        constexpr int Start[4] = {0, 16384, 20480, 21504};
        const float x = ref_pts[qi * 8 + l * 2 + 0] * (float)Wl - 0.5f
                      + off[qi * 256 + h * 32 + lp * 2 + 0];
        const float y = ref_pts[qi * 8 + l * 2 + 1] * (float)Wl - 0.5f
                      + off[qi * 256 + h * 32 + lp * 2 + 1];
        const float xf = floorf(x), yf = floorf(y);
        const float fx = x - xf, fy = y - yf;
        const int x0 = (int)xf, y0 = (int)yf;
        const int xb = min(max(x0, 0), Wl - 2);
        const int yb = min(max(y0, 0), Wl - 2);
        const float wx0 = (xb == x0) ? (1.f - fx) : ((xb == x0 + 1) ? fx : 0.f);
        const float wx1 = (xb + 1 == x0) ? (1.f - fx) : ((xb == x0) ? fx : 0.f);
        const float wy0 = w * ((yb == y0) ? (1.f - fy) : ((yb == y0 + 1) ? fy : 0.f));
        const float wy1 = w * ((yb + 1 == y0) ? (1.f - fy) : ((yb == y0) ? fy : 0.f));

        const int row = n * LIN + Start[l] + yb * Wl + xb;
        s_base[t]  = (h * M_VAL + row) * HDIM;
        s_wx[t][0] = wx0; s_wx[t][1] = wx1;
        s_wy[t][0] = wy0; s_wy[t][1] = wy1;
    }
    __syncthreads();

    {   // phase 2
        const int h = t >> 4, cp = t & 15;
        const int side = cp >> 3, ch4 = (cp & 7) * 4;
        float a0 = 0.f, a1 = 0.f, a2 = 0.f, a3 = 0.f;
        #pragma unroll
        for (int lp = 0; lp < 16; ++lp) {
            const int i  = h * 16 + lp;
            const int rs = (128 >> (lp >> 2)) * HDIM;
            const int b  = s_base[i] + side * HDIM + ch4;
            const float wxs = s_wx[i][side];
            const float w0 = wxs * s_wy[i][0];
            const float w1 = wxs * s_wy[i][1];
            const short4v v0 = *reinterpret_cast<const short4v*>(value + b);
            const short4v v1 = *reinterpret_cast<const short4v*>(value + b + rs);
            a0 += w0 * bf2f(v0[0]) + w1 * bf2f(v1[0]);
            a1 += w0 * bf2f(v0[1]) + w1 * bf2f(v1[1]);
            a2 += w0 * bf2f(v0[2]) + w1 * bf2f(v1[2]);
            a3 += w0 * bf2f(v0[3]) + w1 * bf2f(v1[3]);
        }
        a0 += __shfl_xor(a0, 8, 64);
        a1 += __shfl_xor(a1, 8, 64);
        a2 += __shfl_xor(a2, 8, 64);
        a3 += __shfl_xor(a3, 8, 64);
        if (side == 0) {
            bf16x4 o { __float2bfloat16(a0), __float2bfloat16(a1),
                       __float2bfloat16(a2), __float2bfloat16(a3) };
            *reinterpret_cast<bf16x4*>(samp + (long)qi * D_MODEL + h * HDIM + ch4) = o;
        }
    }
}

// ---------------------------------------------------------------------------
extern "C" void kernel_launch(void* const* d_in, const int* in_sizes, int n_in,
                              void* d_out, int out_size, void* d_ws, size_t ws_size,
                              hipStream_t stream)
{
    const float* pre_tgt  = (const float*)d_in[0];
    const float* pre_qpos = (const float*)d_in[1];
    const float* src      = (const float*)d_in[2];
    const float* ref_pts  = (const float*)d_in[3];
    const unsigned char* pad_mask = (const unsigned char*)d_in[4];
    const float* W_value = (const float*)d_in[7];
    const float* b_value = (const float*)d_in[8];
    const float* W_off   = (const float*)d_in[9];
    const float* b_off   = (const float*)d_in[10];
    const float* W_attn  = (const float*)d_in[11];
    const float* b_attn  = (const float*)d_in[12];
    const float* W_out   = (const float*)d_in[13];
    const float* b_out   = (const float*)d_in[14];
    const float* g1      = (const float*)d_in[15];
    const float* be1     = (const float*)d_in[16];
    const float* W1      = (const float*)d_in[17];
    const float* b1      = (const float*)d_in[18];
    const float* W2      = (const float*)d_in[19];
    const float* b2      = (const float*)d_in[20];
    const float* g3      = (const float*)d_in[21];
    const float* be3     = (const float*)d_in[22];
    float* out = (float*)d_out;

    // opt-in for 128KB dynamic LDS (host-side metadata; graph-capture-safe)
    static bool attr_set = false;
    if (!attr_set) {
        hipFuncSetAttribute((const void*)value_gemm_kernel,
                            hipFuncAttributeMaxDynamicSharedMemorySize, 131072);
        attr_set = true;
    }

    // Workspace layout
    char* w = (char*)d_ws;
    size_t o = 0;
    __hip_bfloat16* value = (__hip_bfloat16*)(w + o); o += (size_t)M_VAL * D_MODEL * 2;   // 89.1 MB head planes
    float* offb    = (float*)(w + o); o += (size_t)M_Q * 256 * 4;
    float* logits  = (float*)(w + o); o += (size_t)M_Q * 128 * 4;
    __hip_bfloat16* samp = (__hip_bfloat16*)(w + o); o += (size_t)M_Q * 256 * 2;
    float* tgt     = (float*)(w + o); o += (size_t)M_Q * 256 * 4;
    short* Wv_t    = (short*)(w + o); o += 256 * 256 * 2;
    short* Wo_t    = (short*)(w + o); o += 256 * 256 * 2;
    short* W1_t    = (short*)(w + o); o += 512 * 256 * 2;
    short* W2_t    = (short*)(w + o); o += 256 * 512 * 2;
    // hidden aliases the (dead-after-sampling) value region
    __hip_bfloat16* hidden = (__hip_bfloat16*)(w + 20000000);  // bf16 [8000][512]

    const dim3 blk(256);

    // 0. weights -> bf16 transposed [N][K]
    transpose_weights_kernel<<<dim3(384), blk, 0, stream>>>(
        W_value, W_out, W1, W2, Wv_t, Wo_t, W1_t, W2_t);

    // 1. value = src @ W_value + b_value (B-stationary, barrier-free)
    value_gemm_kernel<<<dim3(NPANEL / 2), dim3(512), 131072, stream>>>(
        src, Wv_t, b_value, pad_mask, value);

    // 2. fused off/attn projections (f32)
    proj_gemm_kernel<<<dim3(6, M_Q / 64), blk, 0, stream>>>(
        pre_tgt, pre_qpos, W_off, b_off, W_attn, b_attn, offb, logits);

    // 3. fused softmax + bilinear sampling -> samp bf16
    msdeform_sample_kernel<<<dim3(M_Q), dim3(128), 0, stream>>>(
        offb, logits, ref_pts, value, samp);

    // 4. tgt = LN(pre_tgt + samp @ W_out + b_out)   [fused GEMM+LN]
    gemm_ln_kernel<256><<<dim3(M_Q / 64), blk, 0, stream>>>(
        samp, Wo_t, b_out, pre_tgt, g1, be1, tgt);

    // 5. hidden = relu(tgt @ W1 + b1)  (bf16 out)
    ffn1_gemm_kernel<<<dim3(DFFN / BN, M_Q / BM), blk, 0, stream>>>(
        tgt, W1_t, b1, hidden, M_Q, DFFN, 256);

    // 6. out = LN(tgt + hidden @ W2 + b2)   [fused GEMM+LN]
    gemm_ln_kernel<512><<<dim3(M_Q / 64), blk, 0, stream>>>(
        hidden, W2_t, b2, tgt, g3, be3, out);
}